// Round 16
// baseline (227.877 us; speedup 1.0000x reference)
//
#include <hip/hip_runtime.h>

// CrossAttention: B=16, Sq=4096, Dm=512, Skv=77, Dc=768, H=8, Dh=64, inner=512
// Single-pass fp16 MFMA pipeline (R15 structure; out-proj now true 8-phase).
//   0. pad_fill : zero vT si-pad + kbuf row-pad
//   1. transpose4: all W* fp32 [K][512] -> fp16 [512][K] in one launch  (ws)
//   2. gemm_kv  : MERGED k+v projections, 64x64 tiles, 320 blocks       (ws)
//   3. gemm_x16 : q = x(fp32)@Wq -> fp16 [65536][512]  (cvt fused)      (ws)
//   4. attn_h16 : MFMA scores + in-reg fp32 softmax + MFMA PV           (ws)
//   5. gemm_h16_8p: out = attn@Wout + bout -> fp32. m201-style 8-phase:
//      256x256/BK=64/8 waves/128KB LDS; per-phase {ds_reads, 1 half-tile
//      gl_lds, barrier, setprio, 16 MFMA, barrier}; vmcnt(4) once per
//      K-tile (never 0 in steady state); XOR swizzle via pre-swizzled
//      global source + swizzled ds_read (same involution both sides).

typedef unsigned short u16;
typedef unsigned int u32;
typedef _Float16 f16;
typedef __attribute__((ext_vector_type(8))) _Float16 half8;
typedef __attribute__((ext_vector_type(4))) _Float16 half4;
typedef __attribute__((ext_vector_type(4))) float f32x4;

__device__ __forceinline__ f32x4 mfma16h(half8 a, half8 b, f32x4 c) {
    return __builtin_amdgcn_mfma_f32_16x16x32_f16(a, b, c, 0, 0, 0);
}
// async global->LDS, 16B per lane; LDS dest = wave-uniform base + lane*16
__device__ __forceinline__ void gl_lds16(const f16* g, f16* l) {
    __builtin_amdgcn_global_load_lds(
        (const __attribute__((address_space(1))) void*)g,
        (__attribute__((address_space(3))) void*)l, 16, 0, 0);
}

// ---------------- pad fill ----------------
__global__ __launch_bounds__(256) void pad_fill(
    f16* __restrict__ vT, f16* __restrict__ kbuf)
{
    const int nv = 16 * 512 * 19;
    int i = blockIdx.x * 256 + threadIdx.x;
    if (i < nv) {
        int g = i / 19, s = i - g * 19;
        vT[(size_t)g * 96 + 77 + s] = (f16)0.f;
    } else {
        int j = i - nv;
        if (j < 8 * 512) kbuf[(size_t)1232 * 512 + j] = (f16)0.f;
    }
}

// ---------------- all 4 weight transposes -> fp16, one launch ----------------
__global__ __launch_bounds__(256) void transpose4(
    const float* __restrict__ Wq, const float* __restrict__ Wk,
    const float* __restrict__ Wv, const float* __restrict__ Wo,
    f16* __restrict__ WqT, f16* __restrict__ WkT,
    f16* __restrict__ WvT, f16* __restrict__ WoT)
{
    int idx = blockIdx.x * 256 + threadIdx.x;
    const float* W; f16* T; int K; int base;
    if (idx < 262144)        { W = Wq; T = WqT; K = 512; base = 0; }
    else if (idx < 655360)   { W = Wk; T = WkT; K = 768; base = 262144; }
    else if (idx < 1048576)  { W = Wv; T = WvT; K = 768; base = 655360; }
    else if (idx < 1310720)  { W = Wo; T = WoT; K = 512; base = 1048576; }
    else return;
    int j = idx - base;
    int n = j / K, k = j - n * K;
    T[j] = (f16)W[(size_t)k * 512 + n];
}

// ---------------- MERGED k/v projection (R15) ----------------
__global__ __launch_bounds__(256) void gemm_kv(
    const float* __restrict__ A, const f16* __restrict__ Bt,
    f16* __restrict__ kbuf, f16* __restrict__ vT)
{
    __shared__ f16 lA[64 * 40];
    __shared__ f16 lB[64 * 40];

    const int t = threadIdx.x;
    const int lane = t & 63;
    const int w = t >> 6;
    const int wr = w >> 1, wc = w & 1;
    const int m0 = blockIdx.x * 64, n0 = blockIdx.y * 64;
    const int ar = lane & 15;
    const int kc = (lane >> 4) << 3;

    const int srow = t >> 2;
    const int sc8  = (t & 3) << 3;

    f32x4 acc[2][2] = {};

    for (int k0 = 0; k0 < 768; k0 += 32) {
        float4 v0 = make_float4(0.f, 0.f, 0.f, 0.f);
        float4 v1 = make_float4(0.f, 0.f, 0.f, 0.f);
        int gr = m0 + srow;
        if (gr < 1232) {
            v0 = *(const float4*)(A + (size_t)gr * 768 + k0 + sc8);
            v1 = *(const float4*)(A + (size_t)gr * 768 + k0 + sc8 + 4);
        }
        half8 ha = {(f16)v0.x, (f16)v0.y, (f16)v0.z, (f16)v0.w,
                    (f16)v1.x, (f16)v1.y, (f16)v1.z, (f16)v1.w};
        *(half8*)(lA + srow * 40 + sc8) = ha;
        *(half8*)(lB + srow * 40 + sc8) =
            *(const half8*)(Bt + (size_t)(n0 + srow) * 768 + k0 + sc8);
        __syncthreads();

        half8 fa[2], fb[2];
        #pragma unroll
        for (int m = 0; m < 2; ++m)
            fa[m] = *(const half8*)(lA + (wr * 32 + m * 16 + ar) * 40 + kc);
        #pragma unroll
        for (int n = 0; n < 2; ++n)
            fb[n] = *(const half8*)(lB + (wc * 32 + n * 16 + ar) * 40 + kc);
        #pragma unroll
        for (int m = 0; m < 2; ++m)
            #pragma unroll
            for (int n = 0; n < 2; ++n)
                acc[m][n] = mfma16h(fa[m], fb[n], acc[m][n]);
        __syncthreads();
    }

    #pragma unroll
    for (int n = 0; n < 2; ++n) {
        int col = n0 + wc * 32 + n * 16 + ar;
        #pragma unroll
        for (int m = 0; m < 2; ++m) {
            #pragma unroll
            for (int r = 0; r < 4; ++r) {
                int row = m0 + wr * 32 + m * 16 + ((lane >> 4) << 2) + r;
                if (row < 1232) {
                    f16 v = (f16)acc[m][n][r];
                    if (col < 512) {
                        kbuf[(size_t)row * 512 + col] = v;
                    } else {
                        int bb = row / 77;
                        int si = row - bb * 77;
                        vT[((size_t)bb * 512 + (col - 512)) * 96 + si] = v;
                    }
                }
            }
        }
    }
}

// ---------------- q-proj GEMM: fused fp32->fp16, 128x256 tile (R12) --------
__global__ __launch_bounds__(256, 2) void gemm_x16(
    const float* __restrict__ A, const f16* __restrict__ B,
    f16* __restrict__ CHalf, int M, int N, int K)
{
    __shared__ f16 sA[2][128 * 32];
    __shared__ f16 sB[2][256 * 32];

    const int t = threadIdx.x;
    const int lane = t & 63;
    const int w = t >> 6;
    const int wr = w >> 1, wc = w & 1;

    const int f = blockIdx.x + gridDim.x * blockIdx.y;
    const int cpx = (gridDim.x * gridDim.y) >> 3;
    const int logical = (f & 7) * cpx + (f >> 3);
    const int m0 = (logical / gridDim.x) * 128;
    const int n0 = (logical % gridDim.x) * 256;

    const int ar = lane & 15;
    const int kc = (lane >> 4) << 3;

    const int arow = t >> 1;
    const int acol = (t & 1) << 4;
    const int brow = lane >> 2;
    const int bcol = (lane & 3) << 3;

    f32x4 acc[4][8] = {};
    f32x4 rA[4];

    auto LOAD_A = [&](int kt) {
        const float* p = A + (size_t)(m0 + arow) * K + (kt << 5) + acol;
        #pragma unroll
        for (int j = 0; j < 4; ++j) rA[j] = *(const f32x4*)(p + j * 4);
    };
    auto WRITE_A = [&](int buf) {
        half8 h0 = { (f16)rA[0].x, (f16)rA[0].y, (f16)rA[0].z, (f16)rA[0].w,
                     (f16)rA[1].x, (f16)rA[1].y, (f16)rA[1].z, (f16)rA[1].w };
        half8 h1 = { (f16)rA[2].x, (f16)rA[2].y, (f16)rA[2].z, (f16)rA[2].w,
                     (f16)rA[3].x, (f16)rA[3].y, (f16)rA[3].z, (f16)rA[3].w };
        *(half8*)(&sA[buf][arow * 32 + acol])     = h0;
        *(half8*)(&sA[buf][arow * 32 + acol + 8]) = h1;
    };
    auto STAGE_B = [&](int buf, int kt) {
        #pragma unroll
        for (int j = 0; j < 4; ++j) {
            const int ci = w * 4 + j;
            gl_lds16(B + (size_t)(n0 + ci * 16 + brow) * K + (kt << 5) + bcol,
                     &sB[buf][ci * 512]);
        }
    };

    const int nk = K >> 5;
    LOAD_A(0);
    STAGE_B(0, 0);
    WRITE_A(0);
    __syncthreads();

    int cur = 0;
    for (int kt = 0; kt < nk; ++kt) {
        if (kt + 1 < nk) {
            LOAD_A(kt + 1);
            STAGE_B(cur ^ 1, kt + 1);
        }

        half8 fa[4], fb[8];
        #pragma unroll
        for (int m = 0; m < 4; ++m)
            fa[m] = *(const half8*)(&sA[cur][(wr * 64 + m * 16 + ar) * 32 + kc]);
        #pragma unroll
        for (int n = 0; n < 8; ++n)
            fb[n] = *(const half8*)(&sB[cur][(wc * 128 + n * 16 + ar) * 32 + kc]);

        __builtin_amdgcn_s_setprio(1);
        #pragma unroll
        for (int m = 0; m < 4; ++m)
            #pragma unroll
            for (int n = 0; n < 8; ++n)
                acc[m][n] = mfma16h(fa[m], fb[n], acc[m][n]);
        __builtin_amdgcn_s_setprio(0);

        if (kt + 1 < nk) WRITE_A(cur ^ 1);
        __syncthreads();
        cur ^= 1;
    }

    #pragma unroll
    for (int n = 0; n < 8; ++n) {
        int col = n0 + wc * 128 + n * 16 + ar;
        #pragma unroll
        for (int m = 0; m < 4; ++m) {
            #pragma unroll
            for (int r = 0; r < 4; ++r) {
                int row = m0 + wr * 64 + m * 16 + ((lane >> 4) << 2) + r;
                CHalf[(size_t)row * N + col] = (f16)acc[m][n][r];
            }
        }
    }
}

// ---------------- out-proj GEMM: 256x256 8-phase (m201-style) ----------------
// A fp16 [M][K], B fp16 [N][K]; grid dim3(N/256, M/256), block 512 (8 waves).
// BK=64; LDS = 2 parity x 2 half x [128][64] per operand = 128 KiB.
// Swizzle involution: physical col = logical col ^ ((row&4)?16:0), applied
// on the pre-swizzled global SOURCE (write side) and on ds_read (read side).
// Schedule per tile T (4 phases): q0 reads fb(T)+fa(m0,1), stages A0(T+1);
// q1 fa(m2,3)+A1(T+1); q2 fa(m4,5)+B0(T+2); q3 fa(m6,7)+B1(T+2), then
// vmcnt(4) (leaves B(T+2) in flight; lands A(T+1),B(T+1)).  Overwrite
// safety: a staged half is >=1 barrier after its last reader, whose ds_reads
// are forced complete by MFMA consumption before that barrier.
__global__ __launch_bounds__(512) void gemm_h16_8p(
    const f16* __restrict__ A, const f16* __restrict__ B,
    const float* __restrict__ bias, float* __restrict__ C,
    int M, int N, int K)
{
    __shared__ f16 sA[2][2][128 * 64];   // 64 KB
    __shared__ f16 sB[2][2][128 * 64];   // 64 KB

    const int t = threadIdx.x;
    const int lane = t & 63;
    const int w = t >> 6;       // 0..7
    const int wr = w >> 2;      // 0..1  (M half: 128 rows)
    const int wc = w & 3;       // 0..3  (N quarter: 64 cols)

    // XCD-chunked bijective swizzle (512 blocks, %8==0)
    const int f = blockIdx.x + gridDim.x * blockIdx.y;
    const int cpx = (gridDim.x * gridDim.y) >> 3;
    const int logical = (f & 7) * cpx + (f >> 3);
    const int m0 = (logical / gridDim.x) * 256;
    const int n0 = (logical % gridDim.x) * 256;

    const int ar = lane & 15;
    const int kg = lane >> 4;
    const int kc = kg << 3;
    const int swz = (ar & 4) ? 16 : 0;

    // staging: wave w writes chunks 2w,2w+1 of a half (rows 16w..16w+15);
    // source col pre-swizzled so linear LDS = swizzled layout.
    const int srow = lane >> 3;                                   // 0..7
    const int scol = ((lane & 7) << 3) ^ ((lane >= 32) ? 16 : 0); // f16 col

    f32x4 acc[8][4] = {};

    auto STAGE_A = [&](int tile, int h) {
        const int kb = tile << 6;
        #pragma unroll
        for (int j = 0; j < 2; ++j) {
            const int c = w * 2 + j;
            gl_lds16(A + (size_t)(m0 + h * 128 + c * 8 + srow) * K + kb + scol,
                     &sA[tile & 1][h][c * 512]);
        }
    };
    auto STAGE_B = [&](int tile, int h) {
        const int kb = tile << 6;
        #pragma unroll
        for (int j = 0; j < 2; ++j) {
            const int c = w * 2 + j;
            gl_lds16(B + (size_t)(n0 + h * 128 + c * 8 + srow) * K + kb + scol,
                     &sB[tile & 1][h][c * 512]);
        }
    };

    const int nk = K >> 6;   // 8

    // prologue: A(0),B(0) then B(1) -> 12 loads; wait first 8, B(1) flies
    STAGE_A(0, 0); STAGE_A(0, 1);
    STAGE_B(0, 0); STAGE_B(0, 1);
    STAGE_B(1, 0); STAGE_B(1, 1);
    asm volatile("s_waitcnt vmcnt(4)" ::: "memory");
    __builtin_amdgcn_sched_barrier(0);
    __builtin_amdgcn_s_barrier();
    __builtin_amdgcn_sched_barrier(0);

    #pragma unroll 1
    for (int T = 0; T < nk; ++T) {
        const f16* pA = &sA[T & 1][wr][0];
        const f16* pB = &sB[T & 1][wc >> 1][0];
        const int brow0 = (wc & 1) * 64;
        half8 fb[4][2];

        #pragma unroll
        for (int q = 0; q < 4; ++q) {
            if (q == 0) {
                #pragma unroll
                for (int n = 0; n < 4; ++n)
                    #pragma unroll
                    for (int ks = 0; ks < 2; ++ks)
                        fb[n][ks] = *(const half8*)(pB + (brow0 + n * 16 + ar) * 64
                                                       + ((ks * 32 + kc) ^ swz));
            }
            half8 fa[2][2];
            #pragma unroll
            for (int j = 0; j < 2; ++j)
                #pragma unroll
                for (int ks = 0; ks < 2; ++ks)
                    fa[j][ks] = *(const half8*)(pA + ((q * 2 + j) * 16 + ar) * 64
                                                   + ((ks * 32 + kc) ^ swz));

            if (q == 0)      { if (T + 1 < nk) STAGE_A(T + 1, 0); }
            else if (q == 1) { if (T + 1 < nk) STAGE_A(T + 1, 1); }
            else if (q == 2) { if (T + 2 < nk) STAGE_B(T + 2, 0); }
            else             { if (T + 2 < nk) STAGE_B(T + 2, 1); }

            __builtin_amdgcn_s_barrier();
            __builtin_amdgcn_s_setprio(1);
            #pragma unroll
            for (int j = 0; j < 2; ++j)
                #pragma unroll
                for (int n = 0; n < 4; ++n)
                    #pragma unroll
                    for (int ks = 0; ks < 2; ++ks)
                        acc[q * 2 + j][n] =
                            mfma16h(fa[j][ks], fb[n][ks], acc[q * 2 + j][n]);
            __builtin_amdgcn_s_setprio(0);

            if (q == 3) {
                if (T + 2 < nk) asm volatile("s_waitcnt vmcnt(4)" ::: "memory");
                else            asm volatile("s_waitcnt vmcnt(0)" ::: "memory");
                __builtin_amdgcn_sched_barrier(0);
            }
            __builtin_amdgcn_s_barrier();
            __builtin_amdgcn_sched_barrier(0);
        }
    }

    #pragma unroll
    for (int n = 0; n < 4; ++n) {
        const int col = n0 + wc * 64 + n * 16 + ar;
        const float bv = bias[col];
        #pragma unroll
        for (int m = 0; m < 8; ++m) {
            #pragma unroll
            for (int r = 0; r < 4; ++r) {
                const int row = m0 + wr * 128 + m * 16 + kg * 4 + r;
                C[(size_t)row * N + col] = acc[m][n][r] + bv;
            }
        }
    }
}

// ---------------- MFMA attention (fp16 inputs, fp32 softmax) ----------------
// grid (Sq/128, H, B), block 256 (4 waves, 32 q-rows each); P wave-private.
__global__ __launch_bounds__(256) void attn_h16(
    const f16* __restrict__ q, const f16* __restrict__ k,
    const f16* __restrict__ vT, f16* __restrict__ outA)
{
    constexpr int PST = 104;
    __shared__ f16 sP[4 * 32 * PST];

    const int t = threadIdx.x;
    const int lane = t & 63;
    const int w = t >> 6;
    const int ar = lane & 15;
    const int kg = lane >> 4;
    const int kc = kg << 3;
    const int b = blockIdx.z, head = blockIdx.y;
    const size_t qrow0 = (size_t)b * 4096 + blockIdx.x * 128 + w * 32;

    f32x4 accs[2][5] = {};
    #pragma unroll
    for (int ks = 0; ks < 2; ++ks) {
        const int d = head * 64 + ks * 32 + kc;
        half8 ah[2];
        #pragma unroll
        for (int m = 0; m < 2; ++m)
            ah[m] = *(const half8*)(q + (qrow0 + m * 16 + ar) * 512 + d);
        #pragma unroll
        for (int n = 0; n < 5; ++n) {
            half8 bh = *(const half8*)(k + ((size_t)(b * 77 + n * 16 + ar)) * 512 + d);
            #pragma unroll
            for (int m = 0; m < 2; ++m)
                accs[m][n] = mfma16h(ah[m], bh, accs[m][n]);
        }
    }

    #pragma unroll
    for (int m = 0; m < 2; ++m) {
        #pragma unroll
        for (int r = 0; r < 4; ++r) {
            float mx = -1e30f;
            #pragma unroll
            for (int n = 0; n < 5; ++n) {
                float v = accs[m][n][r] * 0.125f;
                if (n == 4 && ar >= 13) v = -1e30f;
                accs[m][n][r] = v;
                mx = fmaxf(mx, v);
            }
            mx = fmaxf(mx, __shfl_xor(mx, 1));
            mx = fmaxf(mx, __shfl_xor(mx, 2));
            mx = fmaxf(mx, __shfl_xor(mx, 4));
            mx = fmaxf(mx, __shfl_xor(mx, 8));
            float sum = 0.f;
            #pragma unroll
            for (int n = 0; n < 5; ++n) {
                float e = __expf(accs[m][n][r] - mx);
                accs[m][n][r] = e;
                sum += e;
            }
            sum += __shfl_xor(sum, 1);
            sum += __shfl_xor(sum, 2);
            sum += __shfl_xor(sum, 4);
            sum += __shfl_xor(sum, 8);
            float inv = 1.f / sum;
            #pragma unroll
            for (int n = 0; n < 5; ++n) accs[m][n][r] *= inv;
        }
    }

    f16* myP = sP + w * 32 * PST;
    for (int i = lane; i < 32 * 12; i += 64) {
        int row = i / 12, c = 80 + (i % 12) * 2;
        *(u32*)(myP + row * PST + c) = 0;
    }
    #pragma unroll
    for (int m = 0; m < 2; ++m)
        #pragma unroll
        for (int n = 0; n < 5; ++n)
            #pragma unroll
            for (int r = 0; r < 4; ++r)
                myP[(m * 16 + kg * 4 + r) * PST + n * 16 + ar] = (f16)accs[m][n][r];

    f32x4 accp[2][4] = {};
    #pragma unroll
    for (int ks = 0; ks < 3; ++ks) {
        half8 pa[2];
        #pragma unroll
        for (int m = 0; m < 2; ++m)
            pa[m] = *(const half8*)(myP + (m * 16 + ar) * PST + ks * 32 + kc);
        #pragma unroll
        for (int n = 0; n < 4; ++n) {
            half8 bh = *(const half8*)(vT + ((size_t)b * 512 + head * 64 + n * 16 + ar) * 96 + ks * 32 + kc);
            #pragma unroll
            for (int m = 0; m < 2; ++m)
                accp[m][n] = mfma16h(pa[m], bh, accp[m][n]);
        }
    }

    #pragma unroll
    for (int m = 0; m < 2; ++m)
        #pragma unroll
        for (int n = 0; n < 4; ++n)
            #pragma unroll
            for (int r = 0; r < 4; ++r)
                outA[(qrow0 + m * 16 + kg * 4 + r) * 512 + head * 64 + n * 16 + ar]
                    = (f16)accp[m][n][r];
}

extern "C" void kernel_launch(void* const* d_in, const int* in_sizes, int n_in,
                              void* d_out, int out_size, void* d_ws, size_t ws_size,
                              hipStream_t stream)
{
    const float* x    = (const float*)d_in[0];   // [16,4096,512]
    const float* ctx  = (const float*)d_in[1];   // [16,77,768]
    const float* Wq   = (const float*)d_in[2];   // [512,512]
    const float* Wk   = (const float*)d_in[3];   // [768,512]
    const float* Wv   = (const float*)d_in[4];   // [768,512]
    const float* Wout = (const float*)d_in[5];   // [512,512]
    const float* bout = (const float*)d_in[6];   // [512]

    char* ws = (char*)d_ws;
    size_t off = 0;
    auto alloc = [&](size_t bytes) -> void* {
        void* p = ws + off;
        off += (bytes + 255) & ~(size_t)255;
        return p;
    };
    f16* WqT = (f16*)alloc(512 * 512 * 2);
    f16* WkT = (f16*)alloc(768 * 512 * 2);     // adjacent to WvT
    f16* WvT = (f16*)alloc(768 * 512 * 2);
    f16* WoT = (f16*)alloc(512 * 512 * 2);
    f16* kbuf = (f16*)alloc((size_t)1240 * 512 * 2);
    f16* vT   = (f16*)alloc((size_t)16 * 512 * 96 * 2);
    f16* qh   = (f16*)alloc((size_t)65536 * 512 * 2);
    f16* attnA = (f16*)alloc((size_t)65536 * 512 * 2);
    (void)ws_size; (void)in_sizes; (void)n_in; (void)out_size;

    // 0. zero pads
    pad_fill<<<dim3(625), dim3(256), 0, stream>>>(vT, kbuf);

    // 1. weight transposes -> fp16
    transpose4<<<dim3(5120), dim3(256), 0, stream>>>(
        Wq, Wk, Wv, Wout, WqT, WkT, WvT, WoT);

    // 2. merged k/v projection
    gemm_kv<<<dim3(20, 16), dim3(256), 0, stream>>>(ctx, WkT, kbuf, vT);

    // 3. q projection (cvt fused)
    gemm_x16<<<dim3(2, 512), dim3(256), 0, stream>>>(
        x, WqT, qh, 65536, 512, 512);

    // 4. attention
    attn_h16<<<dim3(32, 8, 16), dim3(256), 0, stream>>>(qh, kbuf, vT, attnA);

    // 5. output projection + bias -> d_out fp32 (8-phase pipeline)
    gemm_h16_8p<<<dim3(2, 256), dim3(512), 0, stream>>>(
        attnA, WoT, bout, (float*)d_out, 65536, 512, 512);
}